// Round 10
// baseline (158.783 us; speedup 1.0000x reference)
//
#include <hip/hip_runtime.h>
#include <hip/hip_bf16.h>

#define N_NODES 100000
#define N_EDGES 1600000
#define IN_DIM  256
#define OUT_DIM 128

#define GEMM_ROWS   64
#define GEMM_BLOCKS ((N_NODES + GEMM_ROWS - 1) / GEMM_ROWS)   // 1563

#define NBUCK   196                                // ceil(100000 / 512)
#define BSHIFT  9                                  // 512 nodes per bucket
#define BCAP    10240                              // per-bucket capacity (mean 8192)
#define BSTRIDE 16                                 // bcur padding: 1 line per bucket
#define EPB     2048                               // edges per coarse block
#define BIN_BLOCKS ((N_EDGES + EPB - 1) / EPB)     // 782

typedef __attribute__((ext_vector_type(8))) short bf16x8;
typedef __attribute__((ext_vector_type(4))) float f32x4;

__device__ __forceinline__ ushort f2bf(float f) {
    union { float f; unsigned u; } v; v.f = f;
    unsigned r = v.u + 0x7FFF + ((v.u >> 16) & 1);   // RNE
    return (ushort)(r >> 16);
}
__device__ __forceinline__ float bflo(unsigned u) {
    union { unsigned u; float f; } v; v.u = u << 16; return v.f;
}
__device__ __forceinline__ float bfhi(unsigned u) {
    union { unsigned u; float f; } v; v.u = u & 0xFFFF0000u; return v.f;
}

// ---------------- Pack W[256,128] f32 -> bf16 fragment-major ---------------
__global__ __launch_bounds__(256) void pack_w(const float* __restrict__ W,
                                              ushort* __restrict__ Wp) {
    const int t = blockIdx.x * 256 + threadIdx.x;
    if (t >= 4096) return;
    const int kk = t >> 9, n = (t >> 6) & 7, l = t & 63;
    const int kbase = kk * 32 + (l >> 4) * 8;
    const int col   = n * 16 + (l & 15);
    ushort* o = Wp + (size_t)t * 8;
#pragma unroll
    for (int j = 0; j < 8; ++j)
        o[j] = f2bf(W[(size_t)(kbase + j) * OUT_DIM + col]);
}

// ---------------- Standalone MFMA GEMM (32 KB LDS, high occupancy) ---------
__global__ __launch_bounds__(256) void gemm(const float* __restrict__ X,
                                            const bf16x8* __restrict__ Bp,
                                            ushort* __restrict__ H) {
    __shared__ ushort xt[GEMM_ROWS * IN_DIM];      // 32 KB

    const int row0 = blockIdx.x * GEMM_ROWS;
    const int tid  = threadIdx.x;

    // stage: batched loads, convert f32->bf16, swizzled LDS store
    float4 v[16];
#pragma unroll
    for (int it = 0; it < 16; ++it) {
        const int tr = it * 4 + (tid >> 6);
        int grow = row0 + tr; if (grow >= N_NODES) grow = N_NODES - 1;
        v[it] = *reinterpret_cast<const float4*>(X + (size_t)grow * IN_DIM + (tid & 63) * 4);
    }
#pragma unroll
    for (int it = 0; it < 16; ++it) {
        const int tr = it * 4 + (tid >> 6);
        const int tc = (tid & 63) * 4;
        ushort4 b4;
        b4.x = f2bf(v[it].x); b4.y = f2bf(v[it].y);
        b4.z = f2bf(v[it].z); b4.w = f2bf(v[it].w);
        const int byte = (tr * 512 + tc * 2) ^ ((tr & 7) << 4);
        *reinterpret_cast<ushort4*>((char*)xt + byte) = b4;
    }
    __syncthreads();

    const int lane = tid & 63;
    const int wid  = tid >> 6;
    const int wr   = wid >> 1;                     // row half 0..1
    const int wc   = wid & 1;                      // col half 0..1
    const int rlo  = lane & 15;
    const int kseg = lane >> 4;
    const int rl0  = wr * 32 + rlo;                // A-frag local rows
    const int rl1  = rl0 + 16;
    const int rxor = (rlo & 7) << 4;

    f32x4 acc[2][4] = {};

    for (int kk = 0; kk < 8; ++kk) {
        const int cb2 = (kk * 64 + kseg * 16) ^ rxor;
        const bf16x8 A0 = *reinterpret_cast<const bf16x8*>((const char*)xt + rl0 * 512 + cb2);
        const bf16x8 A1 = *reinterpret_cast<const bf16x8*>((const char*)xt + rl1 * 512 + cb2);
        const bf16x8* bbase = Bp + (size_t)(kk * 8 + wc * 4) * 64 + lane;
#pragma unroll
        for (int n = 0; n < 4; ++n) {
            const bf16x8 Bf = bbase[(size_t)n * 64];
            acc[0][n] = __builtin_amdgcn_mfma_f32_16x16x32_bf16(A0, Bf, acc[0][n], 0, 0, 0);
            acc[1][n] = __builtin_amdgcn_mfma_f32_16x16x32_bf16(A1, Bf, acc[1][n], 0, 0, 0);
        }
    }

    // C/D layout: col = (wc*4+n)*16 + rlo, row = wr*32 + i*16 + kseg*4 + r
#pragma unroll
    for (int i = 0; i < 2; ++i) {
#pragma unroll
        for (int r = 0; r < 4; ++r) {
            const int row = row0 + wr * 32 + i * 16 + kseg * 4 + r;
            if (row < N_NODES) {
#pragma unroll
                for (int n = 0; n < 4; ++n)
                    H[(size_t)row * OUT_DIM + (wc * 4 + n) * 16 + rlo] = f2bf(acc[i][n][r]);
            }
        }
    }
}

// ---------------- Standalone coarse dst-bucket binning (high occupancy) ----
__global__ __launch_bounds__(256) void coarse_bin(const int* __restrict__ esrc,
                                                  const int* __restrict__ edst,
                                                  const float* __restrict__ eval,
                                                  int* __restrict__ bcur,
                                                  int2* __restrict__ binned) {
    __shared__ int cnt[NBUCK];                     // 784 B
    __shared__ int sbase[NBUCK];
    const int cb  = blockIdx.x * EPB;
    const int lim = (N_EDGES - cb < EPB) ? (N_EDGES - cb) : EPB;
    const int tid = threadIdx.x;

    if (tid < NBUCK) cnt[tid] = 0;
    __syncthreads();
    for (int i = tid; i < lim; i += 256)
        atomicAdd(&cnt[edst[cb + i] >> BSHIFT], 1);
    __syncthreads();
    if (tid < NBUCK) {
        const int c = cnt[tid];
        sbase[tid] = c ? atomicAdd(&bcur[tid * BSTRIDE], c) : 0;
        cnt[tid] = 0;
    }
    __syncthreads();
    for (int i = tid; i < lim; i += 256) {
        const int d  = edst[cb + i];
        const int bb = d >> BSHIFT;
        const int pos = sbase[bb] + atomicAdd(&cnt[bb], 1);
        if (pos < BCAP) {
            int2 rec;
            rec.x = esrc[cb + i] | ((d & 511) << 20);
            rec.y = __float_as_int(eval[cb + i]);
            binned[(size_t)bb * BCAP + pos] = rec;
        }
    }
}

// ---------------- Tiny scan: 196 bucket sizes -> exclusive bases -----------
__global__ __launch_bounds__(256) void scan_buckets(const int* __restrict__ bcur,
                                                    int* __restrict__ gbase) {
    __shared__ int ws[4];
    const int tid = threadIdx.x, lane = tid & 63, wid = tid >> 6;
    const int v = (tid < NBUCK) ? bcur[tid * BSTRIDE] : 0;
    int sv = v;
#pragma unroll
    for (int d = 1; d < 64; d <<= 1) {
        const int t = __shfl_up(sv, d, 64);
        if (lane >= d) sv += t;
    }
    if (lane == 63) ws[wid] = sv;
    __syncthreads();
    int wx = 0;
#pragma unroll
    for (int w = 0; w < 4; ++w) if (w < wid) wx += ws[w];
    if (tid < NBUCK) gbase[tid] = wx + sv - v;     // exclusive
}

// ------- Fine pass: per-bucket LDS node-hist + scan -> offsets + CSR -------
__global__ __launch_bounds__(1024) void bin_fine(const int* __restrict__ bcur,
                                                 const int* __restrict__ gbase,
                                                 const int2* __restrict__ binned,
                                                 int* __restrict__ offsets,
                                                 int2* __restrict__ recs) {
    __shared__ int nh[512];
    __shared__ int cur[512];
    __shared__ int ws[4];
    const int b   = blockIdx.x;
    const int tid = threadIdx.x, lane = tid & 63, wid = tid >> 6;
    const int node0 = b << BSHIFT;
    int nn = N_NODES - node0; if (nn > 512) nn = 512;
    int size = bcur[b * BSTRIDE]; if (size > BCAP) size = BCAP;
    const int2* in = binned + (size_t)b * BCAP;
    const int base_out = gbase[b];

    if (tid < 512) nh[tid] = 0;
    __syncthreads();
    for (int k = tid; k < size; k += 1024)
        atomicAdd(&nh[(in[k].x >> 20) & 511], 1);
    __syncthreads();

    // exclusive scan over nh[0..511]; threads 0..255 own pair (2t, 2t+1)
    int a0 = 0, ts = 0, sv = 0;
    if (tid < 256) {
        a0 = nh[2 * tid];
        const int a1 = nh[2 * tid + 1];
        ts = a0 + a1;
        sv = ts;
#pragma unroll
        for (int d = 1; d < 64; d <<= 1) {
            const int t = __shfl_up(sv, d, 64);
            if (lane >= d) sv += t;
        }
        if (lane == 63) ws[wid] = sv;
    }
    __syncthreads();
    if (tid < 256) {
        int wx = 0;
#pragma unroll
        for (int w = 0; w < 4; ++w) if (w < wid) wx += ws[w];
        const int ex = wx + sv - ts;               // exclusive prefix of pair
        cur[2 * tid]     = base_out + ex;
        cur[2 * tid + 1] = base_out + ex + a0;
        if (2 * tid < nn)     offsets[node0 + 2 * tid]     = base_out + ex;
        if (2 * tid + 1 < nn) offsets[node0 + 2 * tid + 1] = base_out + ex + a0;
    }
    if (b == 0 && tid == 0) offsets[N_NODES] = N_EDGES;
    __syncthreads();

    for (int k = tid; k < size; k += 1024) {
        const int2 r = in[k];
        const int pos = atomicAdd(&cur[(r.x >> 20) & 511], 1);
        int2 o; o.x = r.x & 0xFFFFF; o.y = r.y;
        recs[pos] = o;
    }
}

// ---------------- SpMM pull (bf16 H): one wave per dst node, ReLU fused ----
__global__ __launch_bounds__(256) void spmm_pull(const ushort* __restrict__ H,
                                                 const int* __restrict__ offsets,
                                                 const int2* __restrict__ recs,
                                                 float* __restrict__ out) {
    const int node = (blockIdx.x * 256 + threadIdx.x) >> 6;
    const int lane = threadIdx.x & 63;
    if (node >= N_NODES) return;

    const int beg = offsets[node];
    const int end = offsets[node + 1];

    float ax = 0.0f, ay = 0.0f;
    int e = beg;
    for (; e + 3 < end; e += 4) {
        const int2 r0 = recs[e + 0];
        const int2 r1 = recs[e + 1];
        const int2 r2 = recs[e + 2];
        const int2 r3 = recs[e + 3];
        const unsigned h0 = *(const unsigned*)(H + (size_t)r0.x * OUT_DIM + lane * 2);
        const unsigned h1 = *(const unsigned*)(H + (size_t)r1.x * OUT_DIM + lane * 2);
        const unsigned h2 = *(const unsigned*)(H + (size_t)r2.x * OUT_DIM + lane * 2);
        const unsigned h3 = *(const unsigned*)(H + (size_t)r3.x * OUT_DIM + lane * 2);
        const float v0 = __int_as_float(r0.y), v1 = __int_as_float(r1.y);
        const float v2 = __int_as_float(r2.y), v3 = __int_as_float(r3.y);
        ax = fmaf(v0, bflo(h0), ax);  ay = fmaf(v0, bfhi(h0), ay);
        ax = fmaf(v1, bflo(h1), ax);  ay = fmaf(v1, bfhi(h1), ay);
        ax = fmaf(v2, bflo(h2), ax);  ay = fmaf(v2, bfhi(h2), ay);
        ax = fmaf(v3, bflo(h3), ax);  ay = fmaf(v3, bfhi(h3), ay);
    }
    for (; e < end; ++e) {
        const int2 r0 = recs[e];
        const float v0 = __int_as_float(r0.y);
        const unsigned h0 = *(const unsigned*)(H + (size_t)r0.x * OUT_DIM + lane * 2);
        ax = fmaf(v0, bflo(h0), ax);  ay = fmaf(v0, bfhi(h0), ay);
    }

    float2 r;
    r.x = fmaxf(ax, 0.0f);
    r.y = fmaxf(ay, 0.0f);
    *reinterpret_cast<float2*>(out + (size_t)node * OUT_DIM + lane * 2) = r;
}

extern "C" void kernel_launch(void* const* d_in, const int* in_sizes, int n_in,
                              void* d_out, int out_size, void* d_ws, size_t ws_size,
                              hipStream_t stream) {
    const float* X    = (const float*)d_in[0];   // [N_NODES, IN_DIM]
    const float* W    = (const float*)d_in[1];   // [IN_DIM, OUT_DIM]
    const int*   esrc = (const int*)d_in[2];     // [N_EDGES]
    const int*   edst = (const int*)d_in[3];     // [N_EDGES]
    const float* eval = (const float*)d_in[4];   // [N_EDGES]
    float*       out  = (float*)d_out;           // [N_NODES, OUT_DIM]

    // Workspace layout (~55.4 MB)
    char* ws = (char*)d_ws;
    ushort* Hb     = (ushort*)ws;  ws += (size_t)N_NODES * OUT_DIM * sizeof(ushort);   // 25.6 MB
    ushort* Wp     = (ushort*)ws;  ws += (size_t)4096 * 8 * sizeof(ushort);            // 64 KB
    int*    offsets= (int*)ws;     ws += (((size_t)(N_NODES + 1) * 4 + 127) & ~(size_t)127);
    int*    bcur   = (int*)ws;     ws += (size_t)NBUCK * BSTRIDE * 4;                  // 12.5 KB padded
    int*    gbase  = (int*)ws;     ws += ((NBUCK * 4 + 127) & ~127);
    int2*   binned = (int2*)ws;    ws += (size_t)NBUCK * BCAP * sizeof(int2);          // 16.1 MB
    int2*   recs   = (int2*)ws;    // 12.8 MB

    // 1) Pack W; zero bucket cursors; coarse binning (own launch, 32 waves/CU)
    pack_w<<<16, 256, 0, stream>>>(W, Wp);
    hipMemsetAsync(bcur, 0, (size_t)NBUCK * BSTRIDE * 4, stream);
    coarse_bin<<<BIN_BLOCKS, 256, 0, stream>>>(esrc, edst, eval, bcur, binned);

    // 2) GEMM (own launch, ~20 waves/CU)
    gemm<<<GEMM_BLOCKS, 256, 0, stream>>>(X, (const bf16x8*)Wp, Hb);

    // 3) Bucket bases, per-bucket CSR finalize
    scan_buckets<<<1, 256, 0, stream>>>(bcur, gbase);
    bin_fine<<<NBUCK, 1024, 0, stream>>>(bcur, gbase, binned, offsets, recs);

    // 4) Pull-SpMM + ReLU, one wave per node
    spmm_pull<<<(N_NODES * 64 + 255) / 256, 256, 0, stream>>>(Hb, offsets, recs, out);
}

// Round 11
// 134.162 us; speedup vs baseline: 1.1835x; 1.1835x over previous
//
#include <hip/hip_runtime.h>
#include <hip/hip_bf16.h>

#define N_NODES 100000
#define N_EDGES 1600000
#define IN_DIM  256
#define OUT_DIM 128

#define GEMM_ROWS   64
#define GEMM_BLOCKS ((N_NODES + GEMM_ROWS - 1) / GEMM_ROWS)   // 1563

#define NBUCK   196                                // ceil(100000 / 512)
#define BSHIFT  9                                  // 512 nodes per bucket
#define BCAP    10240                              // per-bucket capacity (mean 8192)
#define BSTRIDE 16                                 // bcur padding: 1 line per bucket
#define EPB     2048                               // edges per coarse block
#define BIN_BLOCKS ((N_EDGES + EPB - 1) / EPB)     // 782

typedef __attribute__((ext_vector_type(8))) short bf16x8;
typedef __attribute__((ext_vector_type(4))) float f32x4;

__device__ __forceinline__ ushort f2bf(float f) {
    union { float f; unsigned u; } v; v.f = f;
    unsigned r = v.u + 0x7FFF + ((v.u >> 16) & 1);   // RNE
    return (ushort)(r >> 16);
}
__device__ __forceinline__ float bflo(unsigned u) {
    union { unsigned u; float f; } v; v.u = u << 16; return v.f;
}
__device__ __forceinline__ float bfhi(unsigned u) {
    union { unsigned u; float f; } v; v.u = u & 0xFFFF0000u; return v.f;
}

// ---------------- Pack W[256,128] f32 -> bf16 fragment-major ---------------
__global__ __launch_bounds__(256) void pack_w(const float* __restrict__ W,
                                              ushort* __restrict__ Wp) {
    const int t = blockIdx.x * 256 + threadIdx.x;
    if (t >= 4096) return;
    const int kk = t >> 9, n = (t >> 6) & 7, l = t & 63;
    const int kbase = kk * 32 + (l >> 4) * 8;
    const int col   = n * 16 + (l & 15);
    ushort* o = Wp + (size_t)t * 8;
#pragma unroll
    for (int j = 0; j < 8; ++j)
        o[j] = f2bf(W[(size_t)(kbase + j) * OUT_DIM + col]);
}

// ------- Fused: LDS-staged MFMA GEMM + coarse dst-bucket binning -----------
__global__ __launch_bounds__(256) void gemm_coarse(const float* __restrict__ X,
                                                   const bf16x8* __restrict__ Bp,
                                                   ushort* __restrict__ H,
                                                   const int* __restrict__ esrc,
                                                   const int* __restrict__ edst,
                                                   const float* __restrict__ eval,
                                                   int* __restrict__ bcur,
                                                   int2* __restrict__ binned) {
    __shared__ ushort xt[GEMM_ROWS * IN_DIM];      // 32 KB

    if (blockIdx.x >= GEMM_BLOCKS) {
        // ---- coarse binning: LDS hist over 196 buckets, chunked scatter ----
        int* cnt   = (int*)xt;                     // [NBUCK]
        int* sbase = (int*)xt + 256;               // [NBUCK]
        const int blk = blockIdx.x - GEMM_BLOCKS;
        const int cb  = blk * EPB;
        const int lim = (N_EDGES - cb < EPB) ? (N_EDGES - cb) : EPB;
        const int tid = threadIdx.x;

        if (tid < NBUCK) cnt[tid] = 0;
        __syncthreads();
        for (int i = tid; i < lim; i += 256)
            atomicAdd(&cnt[edst[cb + i] >> BSHIFT], 1);
        __syncthreads();
        if (tid < NBUCK) {
            const int c = cnt[tid];
            sbase[tid] = c ? atomicAdd(&bcur[tid * BSTRIDE], c) : 0;
            cnt[tid] = 0;
        }
        __syncthreads();
        for (int i = tid; i < lim; i += 256) {
            const int d  = edst[cb + i];
            const int bb = d >> BSHIFT;
            const int pos = sbase[bb] + atomicAdd(&cnt[bb], 1);
            if (pos < BCAP) {
                int2 rec;
                rec.x = esrc[cb + i] | ((d & 511) << 20);
                rec.y = __float_as_int(eval[cb + i]);
                binned[(size_t)bb * BCAP + pos] = rec;
            }
        }
        return;
    }

    // ---- GEMM: 64 rows x 128 cols; 4 waves in 2x2 (row-half x col-half) ---
    const int row0 = blockIdx.x * GEMM_ROWS;
    const int tid  = threadIdx.x;

    // stage: batched loads, convert f32->bf16, swizzled LDS store
    float4 v[16];
#pragma unroll
    for (int it = 0; it < 16; ++it) {
        const int tr = it * 4 + (tid >> 6);
        int grow = row0 + tr; if (grow >= N_NODES) grow = N_NODES - 1;
        v[it] = *reinterpret_cast<const float4*>(X + (size_t)grow * IN_DIM + (tid & 63) * 4);
    }
#pragma unroll
    for (int it = 0; it < 16; ++it) {
        const int tr = it * 4 + (tid >> 6);
        const int tc = (tid & 63) * 4;
        ushort4 b4;
        b4.x = f2bf(v[it].x); b4.y = f2bf(v[it].y);
        b4.z = f2bf(v[it].z); b4.w = f2bf(v[it].w);
        const int byte = (tr * 512 + tc * 2) ^ ((tr & 7) << 4);
        *reinterpret_cast<ushort4*>((char*)xt + byte) = b4;
    }
    __syncthreads();

    const int lane = tid & 63;
    const int wid  = tid >> 6;
    const int wr   = wid >> 1;                     // row half 0..1
    const int wc   = wid & 1;                      // col half 0..1
    const int rlo  = lane & 15;
    const int kseg = lane >> 4;
    const int rl0  = wr * 32 + rlo;                // A-frag local rows
    const int rl1  = rl0 + 16;
    const int rxor = (rlo & 7) << 4;

    f32x4 acc[2][4] = {};

    for (int kk = 0; kk < 8; ++kk) {
        const int cb2 = (kk * 64 + kseg * 16) ^ rxor;
        const bf16x8 A0 = *reinterpret_cast<const bf16x8*>((const char*)xt + rl0 * 512 + cb2);
        const bf16x8 A1 = *reinterpret_cast<const bf16x8*>((const char*)xt + rl1 * 512 + cb2);
        const bf16x8* bbase = Bp + (size_t)(kk * 8 + wc * 4) * 64 + lane;
#pragma unroll
        for (int n = 0; n < 4; ++n) {
            const bf16x8 Bf = bbase[(size_t)n * 64];
            acc[0][n] = __builtin_amdgcn_mfma_f32_16x16x32_bf16(A0, Bf, acc[0][n], 0, 0, 0);
            acc[1][n] = __builtin_amdgcn_mfma_f32_16x16x32_bf16(A1, Bf, acc[1][n], 0, 0, 0);
        }
    }

    // C/D layout: col = (wc*4+n)*16 + rlo, row = wr*32 + i*16 + kseg*4 + r
#pragma unroll
    for (int i = 0; i < 2; ++i) {
#pragma unroll
        for (int r = 0; r < 4; ++r) {
            const int row = row0 + wr * 32 + i * 16 + kseg * 4 + r;
            if (row < N_NODES) {
#pragma unroll
                for (int n = 0; n < 4; ++n)
                    H[(size_t)row * OUT_DIM + (wc * 4 + n) * 16 + rlo] = f2bf(acc[i][n][r]);
            }
        }
    }
}

// ---------------- Tiny scan: 196 bucket sizes -> exclusive bases -----------
__global__ __launch_bounds__(256) void scan_buckets(const int* __restrict__ bcur,
                                                    int* __restrict__ gbase) {
    __shared__ int ws[4];
    const int tid = threadIdx.x, lane = tid & 63, wid = tid >> 6;
    const int v = (tid < NBUCK) ? bcur[tid * BSTRIDE] : 0;
    int sv = v;
#pragma unroll
    for (int d = 1; d < 64; d <<= 1) {
        const int t = __shfl_up(sv, d, 64);
        if (lane >= d) sv += t;
    }
    if (lane == 63) ws[wid] = sv;
    __syncthreads();
    int wx = 0;
#pragma unroll
    for (int w = 0; w < 4; ++w) if (w < wid) wx += ws[w];
    if (tid < NBUCK) gbase[tid] = wx + sv - v;     // exclusive
}

// ------- Fine pass: per-bucket LDS node-hist + scan -> offsets + CSR -------
__global__ __launch_bounds__(1024) void bin_fine(const int* __restrict__ bcur,
                                                 const int* __restrict__ gbase,
                                                 const int2* __restrict__ binned,
                                                 int* __restrict__ offsets,
                                                 int2* __restrict__ recs) {
    __shared__ int nh[512];
    __shared__ int cur[512];
    __shared__ int ws[4];
    const int b   = blockIdx.x;
    const int tid = threadIdx.x, lane = tid & 63, wid = tid >> 6;
    const int node0 = b << BSHIFT;
    int nn = N_NODES - node0; if (nn > 512) nn = 512;
    int size = bcur[b * BSTRIDE]; if (size > BCAP) size = BCAP;
    const int2* in = binned + (size_t)b * BCAP;
    const int base_out = gbase[b];

    if (tid < 512) nh[tid] = 0;
    __syncthreads();
    for (int k = tid; k < size; k += 1024)
        atomicAdd(&nh[(in[k].x >> 20) & 511], 1);
    __syncthreads();

    // exclusive scan over nh[0..511]; threads 0..255 own pair (2t, 2t+1)
    int a0 = 0, ts = 0, sv = 0;
    if (tid < 256) {
        a0 = nh[2 * tid];
        const int a1 = nh[2 * tid + 1];
        ts = a0 + a1;
        sv = ts;
#pragma unroll
        for (int d = 1; d < 64; d <<= 1) {
            const int t = __shfl_up(sv, d, 64);
            if (lane >= d) sv += t;
        }
        if (lane == 63) ws[wid] = sv;
    }
    __syncthreads();
    if (tid < 256) {
        int wx = 0;
#pragma unroll
        for (int w = 0; w < 4; ++w) if (w < wid) wx += ws[w];
        const int ex = wx + sv - ts;               // exclusive prefix of pair
        cur[2 * tid]     = base_out + ex;
        cur[2 * tid + 1] = base_out + ex + a0;
        if (2 * tid < nn)     offsets[node0 + 2 * tid]     = base_out + ex;
        if (2 * tid + 1 < nn) offsets[node0 + 2 * tid + 1] = base_out + ex + a0;
    }
    if (b == 0 && tid == 0) offsets[N_NODES] = N_EDGES;
    __syncthreads();

    for (int k = tid; k < size; k += 1024) {
        const int2 r = in[k];
        const int pos = atomicAdd(&cur[(r.x >> 20) & 511], 1);
        int2 o; o.x = r.x & 0xFFFFF; o.y = r.y;
        recs[pos] = o;
    }
}

// ------- SpMM pull: 4 nodes/wave, 16 lanes/node, uint4 gathers, ReLU -------
__global__ __launch_bounds__(256) void spmm_pull(const ushort* __restrict__ H,
                                                 const int* __restrict__ offsets,
                                                 const int2* __restrict__ recs,
                                                 float* __restrict__ out) {
    const int tid   = threadIdx.x;
    const int lane  = tid & 63;
    const int g     = lane >> 4;                   // node group 0..3
    const int c     = lane & 15;                   // 16B col-chunk 0..15
    const int gwave = blockIdx.x * 4 + (tid >> 6);
    const int node  = gwave * 4 + g;
    if (node >= N_NODES) return;

    const int beg = offsets[node];
    const int end = offsets[node + 1];

    float a0 = 0.f, a1 = 0.f, a2 = 0.f, a3 = 0.f;
    float a4 = 0.f, a5 = 0.f, a6 = 0.f, a7 = 0.f;

    int e = beg;
    for (; e + 3 < end; e += 4) {                  // 4-edge unroll per group
        const int2 r0 = recs[e + 0];
        const int2 r1 = recs[e + 1];
        const int2 r2 = recs[e + 2];
        const int2 r3 = recs[e + 3];
        const uint4 h0 = *((const uint4*)(H + (size_t)r0.x * OUT_DIM) + c);
        const uint4 h1 = *((const uint4*)(H + (size_t)r1.x * OUT_DIM) + c);
        const uint4 h2 = *((const uint4*)(H + (size_t)r2.x * OUT_DIM) + c);
        const uint4 h3 = *((const uint4*)(H + (size_t)r3.x * OUT_DIM) + c);
        const float v0 = __int_as_float(r0.y), v1 = __int_as_float(r1.y);
        const float v2 = __int_as_float(r2.y), v3 = __int_as_float(r3.y);
        a0 = fmaf(v0, bflo(h0.x), a0);  a1 = fmaf(v0, bfhi(h0.x), a1);
        a2 = fmaf(v0, bflo(h0.y), a2);  a3 = fmaf(v0, bfhi(h0.y), a3);
        a4 = fmaf(v0, bflo(h0.z), a4);  a5 = fmaf(v0, bfhi(h0.z), a5);
        a6 = fmaf(v0, bflo(h0.w), a6);  a7 = fmaf(v0, bfhi(h0.w), a7);
        a0 = fmaf(v1, bflo(h1.x), a0);  a1 = fmaf(v1, bfhi(h1.x), a1);
        a2 = fmaf(v1, bflo(h1.y), a2);  a3 = fmaf(v1, bfhi(h1.y), a3);
        a4 = fmaf(v1, bflo(h1.z), a4);  a5 = fmaf(v1, bfhi(h1.z), a5);
        a6 = fmaf(v1, bflo(h1.w), a6);  a7 = fmaf(v1, bfhi(h1.w), a7);
        a0 = fmaf(v2, bflo(h2.x), a0);  a1 = fmaf(v2, bfhi(h2.x), a1);
        a2 = fmaf(v2, bflo(h2.y), a2);  a3 = fmaf(v2, bfhi(h2.y), a3);
        a4 = fmaf(v2, bflo(h2.z), a4);  a5 = fmaf(v2, bfhi(h2.z), a5);
        a6 = fmaf(v2, bflo(h2.w), a6);  a7 = fmaf(v2, bfhi(h2.w), a7);
        a0 = fmaf(v3, bflo(h3.x), a0);  a1 = fmaf(v3, bfhi(h3.x), a1);
        a2 = fmaf(v3, bflo(h3.y), a2);  a3 = fmaf(v3, bfhi(h3.y), a3);
        a4 = fmaf(v3, bflo(h3.z), a4);  a5 = fmaf(v3, bfhi(h3.z), a5);
        a6 = fmaf(v3, bflo(h3.w), a6);  a7 = fmaf(v3, bfhi(h3.w), a7);
    }
    for (; e < end; ++e) {
        const int2 r0 = recs[e];
        const float v0 = __int_as_float(r0.y);
        const uint4 h0 = *((const uint4*)(H + (size_t)r0.x * OUT_DIM) + c);
        a0 = fmaf(v0, bflo(h0.x), a0);  a1 = fmaf(v0, bfhi(h0.x), a1);
        a2 = fmaf(v0, bflo(h0.y), a2);  a3 = fmaf(v0, bfhi(h0.y), a3);
        a4 = fmaf(v0, bflo(h0.z), a4);  a5 = fmaf(v0, bfhi(h0.z), a5);
        a6 = fmaf(v0, bflo(h0.w), a6);  a7 = fmaf(v0, bfhi(h0.w), a7);
    }

    float* op = out + (size_t)node * OUT_DIM + c * 8;
    float4 o0, o1;
    o0.x = fmaxf(a0, 0.f); o0.y = fmaxf(a1, 0.f);
    o0.z = fmaxf(a2, 0.f); o0.w = fmaxf(a3, 0.f);
    o1.x = fmaxf(a4, 0.f); o1.y = fmaxf(a5, 0.f);
    o1.z = fmaxf(a6, 0.f); o1.w = fmaxf(a7, 0.f);
    *reinterpret_cast<float4*>(op)     = o0;
    *reinterpret_cast<float4*>(op + 4) = o1;
}

extern "C" void kernel_launch(void* const* d_in, const int* in_sizes, int n_in,
                              void* d_out, int out_size, void* d_ws, size_t ws_size,
                              hipStream_t stream) {
    const float* X    = (const float*)d_in[0];   // [N_NODES, IN_DIM]
    const float* W    = (const float*)d_in[1];   // [IN_DIM, OUT_DIM]
    const int*   esrc = (const int*)d_in[2];     // [N_EDGES]
    const int*   edst = (const int*)d_in[3];     // [N_EDGES]
    const float* eval = (const float*)d_in[4];   // [N_EDGES]
    float*       out  = (float*)d_out;           // [N_NODES, OUT_DIM]

    // Workspace layout (~55.4 MB)
    char* ws = (char*)d_ws;
    ushort* Hb     = (ushort*)ws;  ws += (size_t)N_NODES * OUT_DIM * sizeof(ushort);   // 25.6 MB
    ushort* Wp     = (ushort*)ws;  ws += (size_t)4096 * 8 * sizeof(ushort);            // 64 KB
    int*    offsets= (int*)ws;     ws += (((size_t)(N_NODES + 1) * 4 + 127) & ~(size_t)127);
    int*    bcur   = (int*)ws;     ws += (size_t)NBUCK * BSTRIDE * 4;                  // 12.5 KB padded
    int*    gbase  = (int*)ws;     ws += ((NBUCK * 4 + 127) & ~127);
    int2*   binned = (int2*)ws;    ws += (size_t)NBUCK * BCAP * sizeof(int2);          // 16.1 MB
    int2*   recs   = (int2*)ws;    // 12.8 MB

    // 1) Pack W; zero bucket cursors; fused [GEMM || coarse dst-binning]
    pack_w<<<16, 256, 0, stream>>>(W, Wp);
    hipMemsetAsync(bcur, 0, (size_t)NBUCK * BSTRIDE * 4, stream);
    gemm_coarse<<<GEMM_BLOCKS + BIN_BLOCKS, 256, 0, stream>>>(X, (const bf16x8*)Wp, Hb,
                                                              esrc, edst, eval,
                                                              bcur, binned);

    // 2) Bucket bases, per-bucket CSR finalize
    scan_buckets<<<1, 256, 0, stream>>>(bcur, gbase);
    bin_fine<<<NBUCK, 1024, 0, stream>>>(bcur, gbase, binned, offsets, recs);

    // 3) Pull-SpMM + ReLU: 4 nodes per wave, 16 lanes each
    spmm_pull<<<(N_NODES + 15) / 16, 256, 0, stream>>>(Hb, offsets, recs, out);
}